// Round 18
// baseline (4251.881 us; speedup 1.0000x reference)
//
#include <hip/hip_runtime.h>
#include <math.h>

#define Bz 32
#define Tz 20
#define TMz 19
#define Vz 10000
#define INFLAT 262144   // P*D
#define RELSZ 16384

// workspace float offsets (layout kept from R17; barrier/at2p/gsp regions now unused)
#define WS_PH     0
#define WS_PC     4194304
#define WS_ATT1H  0              // bf16[32*1024*256] (reuses ph after k_reduce3)
#define WS_INFOH  4194304        // f16 [32*1024*256] (reuses pc after k_reduce3)
#define WS_HST    8593920
#define WS_CST0   8602112
#define WS_CSTB0  8610304
#define WS_INTS   8700416        // ordp[32] slp[32]
#define WS_PCHC   8701440        // pC partials (dead after k_reduce3)
#define WS_WG16   8701440        // f16[5*256*1024] = 655,360 floats (reuses pC region)
#define WS_WFC16  9750016        // f16[10000*256] = 1,280,000 floats (optional)
#define WS_END_WFC (9750016 + 1280000)

typedef _Float16 half2_t __attribute__((ext_vector_type(2)));

__device__ __forceinline__ float sigm(float x) { return 1.0f / (1.0f + expf(-x)); }

__device__ __forceinline__ unsigned short f2bf(float f) {
    unsigned int x = __float_as_uint(f);
    unsigned int r = (x + 0x7fffu + ((x >> 16) & 1u)) >> 16;
    return (unsigned short)r;
}
__device__ __forceinline__ float bfl(unsigned int u) { return __uint_as_float(u << 16); }
__device__ __forceinline__ float bfh(unsigned int u) { return __uint_as_float(u & 0xffff0000u); }

__device__ __forceinline__ unsigned short f2h(float f) {
    _Float16 h = (_Float16)f;
    return *(unsigned short*)&h;
}
__device__ __forceinline__ half2_t u2h2(unsigned int v) {
    union { unsigned int u; half2_t h; } x; x.u = v; return x.h;
}

// ---------------- sort ----------------
__global__ void k_sort(const int* __restrict__ lens, float* __restrict__ out_order,
                       int* __restrict__ ord, int* __restrict__ sentlen) {
    if (threadIdx.x == 0 && blockIdx.x == 0) {
        int l[Bz]; bool used[Bz];
        for (int b = 0; b < Bz; ++b) { l[b] = lens[b]; used[b] = false; }
        for (int i = 0; i < Bz; ++i) {
            int best = -1;
            for (int j = 0; j < Bz; ++j)
                if (!used[j] && (best < 0 || l[j] > l[best])) best = j;
            used[best] = true;
            ord[i] = best;
            sentlen[i] = l[best] - 1;
            out_order[i] = (float)best;
        }
    }
}

// ---------------- h0,c0: flat(32,262144) @ W_ih / W_ic (register-staged weights) ----------------
__global__ __launch_bounds__(256) void k_gemv2(const float* __restrict__ X, const int* __restrict__ ord,
                                               const float* __restrict__ W1, const float* __restrict__ W2,
                                               float* __restrict__ p1, float* __restrict__ p2) {
    __shared__ __align__(16) float xsT[512 * 36];
    __shared__ int ords[32];
    int tid = threadIdx.x;
    size_t k0 = (size_t)blockIdx.x * 512;

    if (tid < 32) ords[tid] = ord[tid];
    __syncthreads();

    for (int idx = tid; idx < 4096; idx += 256) {
        int b = idx >> 7, kq = idx & 127;
        float4 v = *(const float4*)&X[(size_t)ords[b] * INFLAT + k0 + kq * 4];
        xsT[(kq * 4 + 0) * 36 + b] = v.x;
        xsT[(kq * 4 + 1) * 36 + b] = v.y;
        xsT[(kq * 4 + 2) * 36 + b] = v.z;
        xsT[(kq * 4 + 3) * 36 + b] = v.w;
    }
    __syncthreads();

    float ah[32], ac[32];
#pragma unroll
    for (int b = 0; b < 32; ++b) { ah[b] = 0.f; ac[b] = 0.f; }

    const float* w1p = W1 + k0 * 256 + tid;
    const float* w2p = W2 + k0 * 256 + tid;
#pragma unroll 4
    for (int k = 0; k < 512; ++k) {
        float w1 = w1p[(size_t)k * 256];
        float w2 = w2p[(size_t)k * 256];
        const float4* xr = (const float4*)&xsT[k * 36];
#pragma unroll
        for (int bq = 0; bq < 8; ++bq) {
            float4 x4 = xr[bq];
            ah[bq * 4 + 0] += x4.x * w1; ac[bq * 4 + 0] += x4.x * w2;
            ah[bq * 4 + 1] += x4.y * w1; ac[bq * 4 + 1] += x4.y * w2;
            ah[bq * 4 + 2] += x4.z * w1; ac[bq * 4 + 2] += x4.z * w2;
            ah[bq * 4 + 3] += x4.w * w1; ac[bq * 4 + 3] += x4.w * w2;
        }
    }
#pragma unroll
    for (int b = 0; b < 32; ++b) {
        size_t o = ((size_t)blockIdx.x * 32 + b) * 256 + tid;
        p1[o] = ah[b];
        p2[o] = ac[b];
    }
}

// ---------------- C0: rel(32,16384) @ W_iC, split-K ----------------
__global__ __launch_bounds__(256) void k_gemvC(const float* __restrict__ R, const int* __restrict__ ord,
                                               const float* __restrict__ W, float* __restrict__ p) {
    __shared__ float xs[32 * 128];
    __shared__ int ords[32];
    int tid = threadIdx.x, bx = blockIdx.x;
    if (tid < 32) ords[tid] = ord[tid];
    __syncthreads();
    int k0 = bx * 128;
    for (int idx = tid; idx < 32 * 128; idx += 256) {
        int b = idx >> 7, kk = idx & 127;
        xs[idx] = R[(size_t)ords[b] * RELSZ + k0 + kk];
    }
    __syncthreads();
    float acc[32];
#pragma unroll
    for (int b = 0; b < 32; ++b) acc[b] = 0.f;
    for (int kk = 0; kk < 128; ++kk) {
        float w = W[(size_t)(k0 + kk) * 256 + tid];
#pragma unroll
        for (int b = 0; b < 32; ++b) acc[b] += xs[b * 128 + kk] * w;
    }
#pragma unroll
    for (int b = 0; b < 32; ++b) p[((size_t)bx * 32 + b) * 256 + tid] = acc[b];
}

// ---------------- combined split-K reduces: h0, c0, C0 ----------------
__global__ __launch_bounds__(256) void k_reduce3(const float* __restrict__ ph, const float* __restrict__ pc,
                                                 const float* __restrict__ pC,
                                                 const float* __restrict__ b_ih, const float* __restrict__ b_ic,
                                                 const float* __restrict__ b_iC,
                                                 float* __restrict__ hst, float* __restrict__ cst,
                                                 float* __restrict__ Cst) {
    int which = blockIdx.x >> 5, b = blockIdx.x & 31, j = threadIdx.x;
    if (which == 0) {
        float s0 = b_ih[j], s1 = 0.f, s2 = 0.f, s3 = 0.f;
        for (int c = 0; c < 512; c += 4) {
            s0 += ph[((size_t)((c + 0) * 32 + b)) * 256 + j];
            s1 += ph[((size_t)((c + 1) * 32 + b)) * 256 + j];
            s2 += ph[((size_t)((c + 2) * 32 + b)) * 256 + j];
            s3 += ph[((size_t)((c + 3) * 32 + b)) * 256 + j];
        }
        hst[b * 256 + j] = s0 + s1 + s2 + s3;
    } else if (which == 1) {
        float s0 = b_ic[j], s1 = 0.f, s2 = 0.f, s3 = 0.f;
        for (int c = 0; c < 512; c += 4) {
            s0 += pc[((size_t)((c + 0) * 32 + b)) * 256 + j];
            s1 += pc[((size_t)((c + 1) * 32 + b)) * 256 + j];
            s2 += pc[((size_t)((c + 2) * 32 + b)) * 256 + j];
            s3 += pc[((size_t)((c + 3) * 32 + b)) * 256 + j];
        }
        cst[b * 256 + j] = s0 + s1 + s2 + s3;
    } else {
        float s0 = b_iC[j], s1 = 0.f, s2 = 0.f, s3 = 0.f;
        for (int c = 0; c < 128; c += 4) {
            s0 += pC[((size_t)((c + 0) * 32 + b)) * 256 + j];
            s1 += pC[((size_t)((c + 1) * 32 + b)) * 256 + j];
            s2 += pC[((size_t)((c + 2) * 32 + b)) * 256 + j];
            s3 += pC[((size_t)((c + 3) * 32 + b)) * 256 + j];
        }
        Cst[b * 256 + j] = s0 + s1 + s2 + s3;
    }
}

// ---------------- W_fc [256][10000] f32 -> wfcT16 [10000][256] f16 (optional) ----------------
__global__ __launch_bounds__(256) void k_wfc16(const float* __restrict__ W_fc,
                                               unsigned short* __restrict__ wfcT16) {
    __shared__ unsigned short tile[16 * 256];
    int tid = threadIdx.x;
    int c0 = blockIdx.x * 16;
    for (int p = 0; p < 16; ++p) {
        int r = p * 16 + (tid >> 4);
        int c = tid & 15;
        tile[c * 256 + r] = f2h(W_fc[(size_t)r * Vz + c0 + c]);
    }
    __syncthreads();
    unsigned int* dst = (unsigned int*)wfcT16 + (size_t)c0 * 128;
    const unsigned int* src = (const unsigned int*)tile;
    for (int i = tid; i < 2048; i += 256) dst[i] = src[i];
}

// ---------------- 5 gate weights [1024][256] f32 -> wg16 [5][256][1024] f16 ----------------
__global__ __launch_bounds__(256) void k_wg16(const float* __restrict__ W_i, const float* __restrict__ W_f,
                                              const float* __restrict__ W_o, const float* __restrict__ W_g1,
                                              const float* __restrict__ W_g2,
                                              unsigned short* __restrict__ wg16) {
    __shared__ unsigned short tile[16 * 1024];
    int tid = threadIdx.x;
    int g = blockIdx.x >> 4;
    int c0 = (blockIdx.x & 15) * 16;
    const float* Wg = (g == 0) ? W_i : (g == 1) ? W_f : (g == 2) ? W_o : (g == 3) ? W_g1 : W_g2;
    for (int p = 0; p < 64; ++p) {
        int r = p * 16 + (tid >> 4);
        int c = tid & 15;
        tile[c * 1024 + r] = f2h(Wg[(size_t)r * 256 + c0 + c]);
    }
    __syncthreads();
    unsigned int* dst = (unsigned int*)wg16 + ((size_t)(g * 256 + c0)) * 512;
    const unsigned int* src = (const unsigned int*)tile;
    for (int i = tid; i < 8192; i += 256) dst[i] = src[i];
}

// ---------------- att1h = bf16(info@W_enc+b_enc); infoh = f16(info_sorted) ----------------
__global__ __launch_bounds__(256) void k_att1(const float* __restrict__ info, const int* __restrict__ ord,
                                              const float* __restrict__ W, const float* __restrict__ bias,
                                              unsigned short* __restrict__ att1h,
                                              unsigned short* __restrict__ infoh) {
    __shared__ __align__(16) float xsT[256 * 36];
    int tid = threadIdx.x;
    int r0 = blockIdx.x * 32;
    int b = r0 >> 10, p0 = r0 & 1023;
    const float* src = info + (size_t)ord[b] * INFLAT + (size_t)p0 * 256;
    for (int idx = tid; idx < 2048; idx += 256) {
        int r = idx >> 6, kq = idx & 63;
        float4 v = *(const float4*)&src[r * 256 + kq * 4];
        xsT[(kq * 4 + 0) * 36 + r] = v.x;
        xsT[(kq * 4 + 1) * 36 + r] = v.y;
        xsT[(kq * 4 + 2) * 36 + r] = v.z;
        xsT[(kq * 4 + 3) * 36 + r] = v.w;
    }
    __syncthreads();
#pragma unroll 4
    for (int r = 0; r < 32; ++r)
        infoh[(size_t)(r0 + r) * 256 + tid] = f2h(xsT[tid * 36 + r]);
    float acc[32];
#pragma unroll
    for (int r = 0; r < 32; ++r) acc[r] = 0.f;
    for (int k = 0; k < 256; ++k) {
        float w = W[k * 256 + tid];
        const float4* xr = (const float4*)&xsT[k * 36];
#pragma unroll
        for (int rq = 0; rq < 8; ++rq) {
            float4 x4 = xr[rq];
            acc[rq * 4 + 0] += x4.x * w;
            acc[rq * 4 + 1] += x4.y * w;
            acc[rq * 4 + 2] += x4.z * w;
            acc[rq * 4 + 3] += x4.w * w;
        }
    }
    float bj = bias[tid];
#pragma unroll
    for (int r = 0; r < 32; ++r)
        att1h[(size_t)(r0 + r) * 256 + tid] = f2bf(acc[r] + bj);
}

// ---------------- per-batch sequential kernel: NO grid syncs ----------------
struct KArgs {
    const float *emb, *W_dec, *b_dec, *W_full, *b_full;
    const float *b_i, *b_f, *b_o, *b_g1, *b_g2;
    const float *W_mlp, *b_mlp, *W_fc, *b_fc;
    const int *caps;
    const unsigned short *att1h, *infoh, *wfcT16, *wg16;   // wfcT16 may be null
    const float *hst, *cst0, *Cst0;
    const int *ord, *slp;
    float *out_pred, *out_alpha;
};

// grid 64: block (b = bid>>1, rep = bid&1). All state in LDS; only pred cols split by rep.
__global__ __launch_bounds__(1024, 1) void k_batch(KArgs a) {
    __shared__ float hs[256], cs[256], Cs[256], at2[256], wfv[256], aw[256], ovs[256];
    __shared__ float ex[1024];
    __shared__ float part[2080];
    __shared__ float gs[1280];
    __shared__ __align__(16) unsigned short x16[1024];
    __shared__ __align__(16) unsigned short h16[256];
    __shared__ float Zs;

    int bid = blockIdx.x, tid = threadIdx.x;
    int b = bid >> 1, rep = bid & 1;
    int ordb = a.ord[b];
    int sl = a.slp[b];
    float bfull = a.b_full[0];

    if (tid < 256) {
        hs[tid] = a.hst[b * 256 + tid];
        cs[tid] = a.cst0[b * 256 + tid];
        Cs[tid] = a.Cst0[b * 256 + tid];
        wfv[tid] = a.W_full[tid];
    }
    __syncthreads();

    const unsigned short* attB = a.att1h + (size_t)b * 1024 * 256;
    const unsigned short* infB = a.infoh + (size_t)b * 1024 * 256;

    for (int t = 0; t < TMz; ++t) {
        // ---- at2 = hs @ W_dec + b_dec (j = tid&255 coalesced on W_dec cols) ----
        {
            int j = tid & 255, q = tid >> 8;
            float s = 0.f;
            const float* wd = a.W_dec + (size_t)(q * 64) * 256 + j;
            for (int k = 0; k < 64; ++k) s += hs[q * 64 + k] * wd[(size_t)k * 256];
            part[q * 256 + j] = s;
        }
        __syncthreads();
        if (tid < 256) at2[tid] = a.b_dec[tid] + part[tid] + part[256 + tid] + part[512 + tid] + part[768 + tid];
        __syncthreads();

        // ---- e + expe: quad-per-row (coalesced 64B units), 4 passes ----
        {
            int sub = tid & 3, pr = tid >> 2;
#pragma unroll 1
            for (int pass = 0; pass < 4; ++pass) {
                int p = pass * 256 + pr;
                const uint4* row = (const uint4*)(attB + (size_t)p * 256);
                float s = 0.f;
#pragma unroll
                for (int c = 0; c < 8; ++c) {
                    int ui = c * 4 + sub;
                    uint4 u = row[ui];
                    const float* A = at2 + ui * 8;
                    const float* W = wfv + ui * 8;
                    s += fmaxf(bfl(u.x) + A[0], 0.f) * W[0] + fmaxf(bfh(u.x) + A[1], 0.f) * W[1]
                       + fmaxf(bfl(u.y) + A[2], 0.f) * W[2] + fmaxf(bfh(u.y) + A[3], 0.f) * W[3]
                       + fmaxf(bfl(u.z) + A[4], 0.f) * W[4] + fmaxf(bfh(u.z) + A[5], 0.f) * W[5]
                       + fmaxf(bfl(u.w) + A[6], 0.f) * W[6] + fmaxf(bfh(u.w) + A[7], 0.f) * W[7];
                }
                s += __shfl_xor(s, 1);
                s += __shfl_xor(s, 2);
                if (sub == 0) ex[p] = expf(s + bfull);
            }
        }
        __syncthreads();

        // ---- Z reduce ----
        if (tid < 256) part[tid] = ex[tid] + ex[256 + tid] + ex[512 + tid] + ex[768 + tid];
        __syncthreads();
        if (tid < 32) {
            float s = 0.f;
#pragma unroll
            for (int k = 0; k < 8; ++k) s += part[tid * 8 + k];
            part[2048 + tid] = s;
        }
        __syncthreads();
        if (tid == 0) {
            float s = 0.f;
#pragma unroll
            for (int k = 0; k < 32; ++k) s += part[2048 + k];
            Zs = s;
        }
        __syncthreads();
        float invZ = 1.0f / Zs;

        // ---- alpha (rep 0 only) ----
        if (rep == 0) {
            float am = (sl > t) ? invZ : 0.f;
            a.out_alpha[((size_t)b * TMz + t) * 1024 + tid] = ex[tid] * am;
        }

        // ---- awf partials (coalesced column access on infoh) ----
        {
            int dp = tid & 127, q = tid >> 7;
            int d0 = dp * 2;
            const unsigned short* ib = infB + (size_t)(q * 128) * 256 + d0;
            float a0 = 0.f, a1 = 0.f;
            for (int p = 0; p < 128; ++p) {
                unsigned int u = *(const unsigned int*)(ib + (size_t)p * 256);
                half2_t hp = u2h2(u);
                float ev = ex[q * 128 + p];
                a0 += ev * (float)hp.x;
                a1 += ev * (float)hp.y;
            }
            part[q * 256 + d0] = a0;
            part[q * 256 + d0 + 1] = a1;
        }
        __syncthreads();
        if (tid < 256) {
            float s = 0.f;
#pragma unroll
            for (int q = 0; q < 8; ++q) s += part[q * 256 + tid];
            aw[tid] = s * invZ;
        }
        __syncthreads();

        // ---- x16 = f16(concat[word, awf, h]) ----
        {
            int cap = a.caps[ordb * Tz + t];
            float v;
            if (tid < 512) v = a.emb[(size_t)cap * 512 + tid];
            else if (tid < 768) v = aw[tid - 512];
            else v = hs[tid - 768];
            x16[tid] = f2h(v);
        }
        __syncthreads();

        // ---- gates: quad-per-col, fdot2, K=1024 ----
        {
            int sub = tid & 3, j = tid >> 2;
            const uint4* xr = (const uint4*)x16;
#pragma unroll 1
            for (int g = 0; g < 5; ++g) {
                const uint4* wcol = (const uint4*)(a.wg16 + ((size_t)(g * 256 + j)) * 1024);
                float s = 0.f;
#pragma unroll 4
                for (int c = 0; c < 32; ++c) {
                    int ui = c * 4 + sub;
                    uint4 w = wcol[ui];
                    uint4 x = xr[ui];
                    s = __builtin_amdgcn_fdot2(u2h2(w.x), u2h2(x.x), s, false);
                    s = __builtin_amdgcn_fdot2(u2h2(w.y), u2h2(x.y), s, false);
                    s = __builtin_amdgcn_fdot2(u2h2(w.z), u2h2(x.z), s, false);
                    s = __builtin_amdgcn_fdot2(u2h2(w.w), u2h2(x.w), s, false);
                }
                s += __shfl_xor(s, 1);
                s += __shfl_xor(s, 2);
                if (sub == 0) {
                    const float* bb = (g == 0) ? a.b_i : (g == 1) ? a.b_f : (g == 2) ? a.b_o : (g == 3) ? a.b_g1 : a.b_g2;
                    gs[g * 256 + j] = bb[j] + s;
                }
            }
        }
        __syncthreads();

        // ---- cell ----
        if (tid < 256) {
            float iv = sigm(gs[tid]), fv = sigm(gs[256 + tid]), ov = sigm(gs[512 + tid]);
            float g1 = tanhf(gs[768 + tid]), g2 = tanhf(gs[1024 + tid]);
            float nc = fv * cs[tid] + iv * g1;
            float nC = fv * Cs[tid] + iv * g2;
            cs[tid] = nc; Cs[tid] = nC;
            part[tid] = nc; part[256 + tid] = nC;
            ovs[tid] = ov;
        }
        __syncthreads();

        // ---- mlp ----
        {
            int j = tid & 255, q = tid >> 8;
            float s = 0.f;
            const float* wm = a.W_mlp + (size_t)(q * 128) * 256 + j;
            for (int k = 0; k < 128; ++k) s += part[q * 128 + k] * wm[(size_t)k * 256];
            part[1024 + q * 256 + j] = s;
        }
        __syncthreads();
        if (tid < 256) {
            float m = a.b_mlp[tid] + part[1024 + tid] + part[1280 + tid] + part[1536 + tid] + part[1792 + tid];
            float hv = ovs[tid] * tanhf(m);
            hs[tid] = hv;
            h16[tid] = f2h(hv);
        }
        __syncthreads();

        // ---- pred: this rep's 5000 cols ----
        {
            bool on = (sl > t);
            float* op = a.out_pred + ((size_t)b * TMz + t) * Vz;
            if (a.wfcT16) {
                int sub = tid & 3, cr = tid >> 2;
                const uint4* hr = (const uint4*)h16;
#pragma unroll 1
                for (int pass = 0; pass < 20; ++pass) {
                    int cid = pass * 256 + cr;
                    int col = rep * 5000 + cid;
                    float s = 0.f;
                    if (cid < 5000) {
                        const uint4* wcol = (const uint4*)(a.wfcT16 + (size_t)col * 256);
#pragma unroll
                        for (int c = 0; c < 8; ++c) {
                            int ui = c * 4 + sub;
                            uint4 w = wcol[ui];
                            uint4 h = hr[ui];
                            s = __builtin_amdgcn_fdot2(u2h2(w.x), u2h2(h.x), s, false);
                            s = __builtin_amdgcn_fdot2(u2h2(w.y), u2h2(h.y), s, false);
                            s = __builtin_amdgcn_fdot2(u2h2(w.z), u2h2(h.z), s, false);
                            s = __builtin_amdgcn_fdot2(u2h2(w.w), u2h2(h.w), s, false);
                        }
                    }
                    s += __shfl_xor(s, 1);
                    s += __shfl_xor(s, 2);
                    if (sub == 0 && cid < 5000)
                        op[col] = on ? (s + a.b_fc[col]) : 0.f;
                }
            } else {
                float acc[5] = {0.f, 0.f, 0.f, 0.f, 0.f};
                for (int k = 0; k < 256; ++k) {
                    float hv = hs[k];
                    const float* wr = a.W_fc + (size_t)k * Vz + rep * 5000;
#pragma unroll
                    for (int uu = 0; uu < 5; ++uu) {
                        int cid = uu * 1024 + tid;
                        if (cid < 5000) acc[uu] += hv * wr[cid];
                    }
                }
#pragma unroll
                for (int uu = 0; uu < 5; ++uu) {
                    int cid = uu * 1024 + tid;
                    if (cid < 5000) {
                        int col = rep * 5000 + cid;
                        op[col] = on ? (acc[uu] + a.b_fc[col]) : 0.f;
                    }
                }
            }
        }
        __syncthreads();
    }
}

extern "C" void kernel_launch(void* const* d_in, const int* in_sizes, int n_in,
                              void* d_out, int out_size, void* d_ws, size_t ws_size,
                              hipStream_t stream) {
    const float* info  = (const float*)d_in[0];
    const float* rel   = (const float*)d_in[1];
    const int*   caps  = (const int*)d_in[2];
    const int*   lens  = (const int*)d_in[3];
    const float* emb   = (const float*)d_in[4];
    const float* W_enc = (const float*)d_in[5];
    const float* b_enc = (const float*)d_in[6];
    const float* W_dec = (const float*)d_in[7];
    const float* b_dec = (const float*)d_in[8];
    const float* W_full= (const float*)d_in[9];
    const float* b_full= (const float*)d_in[10];
    const float* W_i   = (const float*)d_in[11];
    const float* b_i   = (const float*)d_in[12];
    const float* W_f   = (const float*)d_in[13];
    const float* b_f   = (const float*)d_in[14];
    const float* W_o   = (const float*)d_in[15];
    const float* b_o   = (const float*)d_in[16];
    const float* W_g1  = (const float*)d_in[17];
    const float* b_g1  = (const float*)d_in[18];
    const float* W_g2  = (const float*)d_in[19];
    const float* b_g2  = (const float*)d_in[20];
    const float* W_mlp = (const float*)d_in[21];
    const float* b_mlp = (const float*)d_in[22];
    const float* W_fc  = (const float*)d_in[25];
    const float* b_fc  = (const float*)d_in[26];
    const float* W_ih  = (const float*)d_in[27];
    const float* b_ih  = (const float*)d_in[28];
    const float* W_ic  = (const float*)d_in[29];
    const float* b_ic  = (const float*)d_in[30];
    const float* W_iC  = (const float*)d_in[31];
    const float* b_iC  = (const float*)d_in[32];

    float* out = (float*)d_out;
    float* out_pred  = out;
    float* out_alpha = out + (size_t)Bz * TMz * Vz;
    float* out_order = out_alpha + (size_t)Bz * TMz * 1024;

    float* w = (float*)d_ws;
    float* ph   = w + WS_PH;
    float* pcp  = w + WS_PC;
    unsigned short* att1h = (unsigned short*)(w + WS_ATT1H);
    unsigned short* infoh = (unsigned short*)(w + WS_INFOH);
    float* hst  = w + WS_HST;
    float* cst0 = w + WS_CST0;
    float* Cst0 = w + WS_CSTB0;
    int*   ordp = (int*)(w + WS_INTS);
    int*   slp  = ordp + 32;
    float* pC   = w + WS_PCHC;
    unsigned short* wg16   = (unsigned short*)(w + WS_WG16);
    unsigned short* wfcT16 = (unsigned short*)(w + WS_WFC16);

    int useWfc = (ws_size >= (size_t)WS_END_WFC * 4);

    k_sort<<<1, 64, 0, stream>>>(lens, out_order, ordp, slp);
    k_gemv2<<<512, 256, 0, stream>>>(info, ordp, W_ih, W_ic, ph, pcp);
    k_gemvC<<<128, 256, 0, stream>>>(rel, ordp, W_iC, pC);
    k_reduce3<<<96, 256, 0, stream>>>(ph, pcp, pC, b_ih, b_ic, b_iC, hst, cst0, Cst0);
    k_wg16<<<80, 256, 0, stream>>>(W_i, W_f, W_o, W_g1, W_g2, wg16);   // after k_reduce3 (pC dead)
    if (useWfc) k_wfc16<<<625, 256, 0, stream>>>(W_fc, wfcT16);
    k_att1<<<1024, 256, 0, stream>>>(info, ordp, W_enc, b_enc, att1h, infoh);

    KArgs ka;
    ka.emb = emb; ka.W_dec = W_dec; ka.b_dec = b_dec;
    ka.W_full = W_full; ka.b_full = b_full;
    ka.b_i = b_i; ka.b_f = b_f; ka.b_o = b_o; ka.b_g1 = b_g1; ka.b_g2 = b_g2;
    ka.W_mlp = W_mlp; ka.b_mlp = b_mlp; ka.W_fc = W_fc; ka.b_fc = b_fc;
    ka.caps = caps;
    ka.att1h = att1h; ka.infoh = infoh;
    ka.wfcT16 = useWfc ? wfcT16 : (const unsigned short*)0;
    ka.wg16 = wg16;
    ka.hst = hst; ka.cst0 = cst0; ka.Cst0 = Cst0;
    ka.ord = ordp; ka.slp = slp;
    ka.out_pred = out_pred; ka.out_alpha = out_alpha;

    k_batch<<<64, 1024, 0, stream>>>(ka);
}

// Round 19
// 3937.659 us; speedup vs baseline: 1.0798x; 1.0798x over previous
//
#include <hip/hip_runtime.h>
#include <math.h>

#define Bz 32
#define Tz 20
#define TMz 19
#define Vz 10000
#define INFLAT 262144   // P*D
#define RELSZ 16384
#define NBLK 512

// workspace float offsets
#define WS_PH     0
#define WS_PC     4194304
#define WS_ATT1H  0              // bf16[32*1024*256] (reuses ph after k_reduce3)
#define WS_INFOH  4194304        // bf16[32*1024*256] (reuses pc after k_reduce3)
#define WS_EXPE   8388608        // 32768
#define WS_GSP    8430080        // 5*4*32*256 = 163840
#define WS_HST    8593920
#define WS_CST0   8602112
#define WS_CSTB0  8610304
#define WS_AWF2   8634880        // 2 parities x 8192 = 16384
#define WS_ZSUM2  8651264        // 2 parities x 32 = 64
#define WS_INTS   8700416        // ordp[32] slp[32] barmem[64+512]
#define WS_PCHC   8701440        // pC partials (dead after k_reduce3)
#define WS_WG16   8701440        // bf16[5*256*1024] = 655,360 floats (reuses pC region)
#define WS_WFC16  9750016        // bf16[10000*256] = 1,280,000 floats (optional)
#define WS_END_WFC (9750016 + 1280000)

__device__ __forceinline__ float sigm(float x) { return 1.0f / (1.0f + expf(-x)); }

__device__ __forceinline__ unsigned short f2bf(float f) {
    unsigned int x = __float_as_uint(f);
    unsigned int r = (x + 0x7fffu + ((x >> 16) & 1u)) >> 16;
    return (unsigned short)r;
}
__device__ __forceinline__ float bfl(unsigned int u) { return __uint_as_float(u << 16); }
__device__ __forceinline__ float bfh(unsigned int u) { return __uint_as_float(u & 0xffff0000u); }

// Agent-scope accessors for cross-block-communicated state ONLY.
__device__ __forceinline__ float agload(const float* p) {
    return __hip_atomic_load(p, __ATOMIC_RELAXED, __HIP_MEMORY_SCOPE_AGENT);
}
__device__ __forceinline__ void agstore(float* p, float v) {
    __hip_atomic_store(p, v, __ATOMIC_RELAXED, __HIP_MEMORY_SCOPE_AGENT);
}
__device__ __forceinline__ int agloadi(const int* p) {
    return __hip_atomic_load(p, __ATOMIC_RELAXED, __HIP_MEMORY_SCOPE_AGENT);
}
__device__ __forceinline__ void agstorei(int* p, int v) {
    __hip_atomic_store(p, v, __ATOMIC_RELAXED, __HIP_MEMORY_SCOPE_AGENT);
}
__device__ __forceinline__ void agadd(float* p, float v) {
    __hip_atomic_fetch_add(p, v, __ATOMIC_RELAXED, __HIP_MEMORY_SCOPE_AGENT);
}

// Fence-free slot grid barrier (no cache invalidation).
__device__ __forceinline__ void gbar(int* slots, int* root, int gen) {
    asm volatile("s_waitcnt vmcnt(0)" ::: "memory");
    __syncthreads();
    if (blockIdx.x == 0) {
        int i0 = threadIdx.x, i1 = threadIdx.x + 256;
        if (i0 != 0) {
            while (agloadi(&slots[i0]) < gen) __builtin_amdgcn_s_sleep(1);
        }
        while (agloadi(&slots[i1]) < gen) __builtin_amdgcn_s_sleep(1);
        __syncthreads();
        if (threadIdx.x == 0) agstorei(root, gen);
    } else if (threadIdx.x == 0) {
        agstorei(&slots[blockIdx.x], gen);
        while (agloadi(root) < gen) __builtin_amdgcn_s_sleep(2);
    }
    __syncthreads();
    asm volatile("" ::: "memory");
}

// ---------------- sort + barrier init ----------------
__global__ void k_sort(const int* __restrict__ lens, float* __restrict__ out_order,
                       int* __restrict__ ord, int* __restrict__ sentlen, int* __restrict__ barmem) {
    if (threadIdx.x == 0 && blockIdx.x == 0) {
        for (int i = 0; i < 64 + NBLK; ++i) barmem[i] = 0;
        int l[Bz]; bool used[Bz];
        for (int b = 0; b < Bz; ++b) { l[b] = lens[b]; used[b] = false; }
        for (int i = 0; i < Bz; ++i) {
            int best = -1;
            for (int j = 0; j < Bz; ++j)
                if (!used[j] && (best < 0 || l[j] > l[best])) best = j;
            used[best] = true;
            ord[i] = best;
            sentlen[i] = l[best] - 1;
            out_order[i] = (float)best;
        }
    }
}

// ---------------- h0,c0: flat(32,262144) @ W_ih / W_ic (register-staged weights) ----------------
__global__ __launch_bounds__(256) void k_gemv2(const float* __restrict__ X, const int* __restrict__ ord,
                                               const float* __restrict__ W1, const float* __restrict__ W2,
                                               float* __restrict__ p1, float* __restrict__ p2) {
    __shared__ __align__(16) float xsT[512 * 36];
    __shared__ int ords[32];
    int tid = threadIdx.x;
    size_t k0 = (size_t)blockIdx.x * 512;

    if (tid < 32) ords[tid] = ord[tid];
    __syncthreads();

    for (int idx = tid; idx < 4096; idx += 256) {
        int b = idx >> 7, kq = idx & 127;
        float4 v = *(const float4*)&X[(size_t)ords[b] * INFLAT + k0 + kq * 4];
        xsT[(kq * 4 + 0) * 36 + b] = v.x;
        xsT[(kq * 4 + 1) * 36 + b] = v.y;
        xsT[(kq * 4 + 2) * 36 + b] = v.z;
        xsT[(kq * 4 + 3) * 36 + b] = v.w;
    }
    __syncthreads();

    float ah[32], ac[32];
#pragma unroll
    for (int b = 0; b < 32; ++b) { ah[b] = 0.f; ac[b] = 0.f; }

    const float* w1p = W1 + k0 * 256 + tid;
    const float* w2p = W2 + k0 * 256 + tid;
#pragma unroll 4
    for (int k = 0; k < 512; ++k) {
        float w1 = w1p[(size_t)k * 256];
        float w2 = w2p[(size_t)k * 256];
        const float4* xr = (const float4*)&xsT[k * 36];
#pragma unroll
        for (int bq = 0; bq < 8; ++bq) {
            float4 x4 = xr[bq];
            ah[bq * 4 + 0] += x4.x * w1; ac[bq * 4 + 0] += x4.x * w2;
            ah[bq * 4 + 1] += x4.y * w1; ac[bq * 4 + 1] += x4.y * w2;
            ah[bq * 4 + 2] += x4.z * w1; ac[bq * 4 + 2] += x4.z * w2;
            ah[bq * 4 + 3] += x4.w * w1; ac[bq * 4 + 3] += x4.w * w2;
        }
    }
#pragma unroll
    for (int b = 0; b < 32; ++b) {
        size_t o = ((size_t)blockIdx.x * 32 + b) * 256 + tid;
        p1[o] = ah[b];
        p2[o] = ac[b];
    }
}

// ---------------- C0: rel(32,16384) @ W_iC, split-K ----------------
__global__ __launch_bounds__(256) void k_gemvC(const float* __restrict__ R, const int* __restrict__ ord,
                                               const float* __restrict__ W, float* __restrict__ p) {
    __shared__ float xs[32 * 128];
    __shared__ int ords[32];
    int tid = threadIdx.x, bx = blockIdx.x;
    if (tid < 32) ords[tid] = ord[tid];
    __syncthreads();
    int k0 = bx * 128;
    for (int idx = tid; idx < 32 * 128; idx += 256) {
        int b = idx >> 7, kk = idx & 127;
        xs[idx] = R[(size_t)ords[b] * RELSZ + k0 + kk];
    }
    __syncthreads();
    float acc[32];
#pragma unroll
    for (int b = 0; b < 32; ++b) acc[b] = 0.f;
    for (int kk = 0; kk < 128; ++kk) {
        float w = W[(size_t)(k0 + kk) * 256 + tid];
#pragma unroll
        for (int b = 0; b < 32; ++b) acc[b] += xs[b * 128 + kk] * w;
    }
#pragma unroll
    for (int b = 0; b < 32; ++b) p[((size_t)bx * 32 + b) * 256 + tid] = acc[b];
}

// ---------------- combined split-K reduces: h0, c0, C0 ----------------
__global__ __launch_bounds__(256) void k_reduce3(const float* __restrict__ ph, const float* __restrict__ pc,
                                                 const float* __restrict__ pC,
                                                 const float* __restrict__ b_ih, const float* __restrict__ b_ic,
                                                 const float* __restrict__ b_iC,
                                                 float* __restrict__ hst, float* __restrict__ cst,
                                                 float* __restrict__ Cst) {
    int which = blockIdx.x >> 5, b = blockIdx.x & 31, j = threadIdx.x;
    if (which == 0) {
        float s0 = b_ih[j], s1 = 0.f, s2 = 0.f, s3 = 0.f;
        for (int c = 0; c < 512; c += 4) {
            s0 += ph[((size_t)((c + 0) * 32 + b)) * 256 + j];
            s1 += ph[((size_t)((c + 1) * 32 + b)) * 256 + j];
            s2 += ph[((size_t)((c + 2) * 32 + b)) * 256 + j];
            s3 += ph[((size_t)((c + 3) * 32 + b)) * 256 + j];
        }
        hst[b * 256 + j] = s0 + s1 + s2 + s3;
    } else if (which == 1) {
        float s0 = b_ic[j], s1 = 0.f, s2 = 0.f, s3 = 0.f;
        for (int c = 0; c < 512; c += 4) {
            s0 += pc[((size_t)((c + 0) * 32 + b)) * 256 + j];
            s1 += pc[((size_t)((c + 1) * 32 + b)) * 256 + j];
            s2 += pc[((size_t)((c + 2) * 32 + b)) * 256 + j];
            s3 += pc[((size_t)((c + 3) * 32 + b)) * 256 + j];
        }
        cst[b * 256 + j] = s0 + s1 + s2 + s3;
    } else {
        float s0 = b_iC[j], s1 = 0.f, s2 = 0.f, s3 = 0.f;
        for (int c = 0; c < 128; c += 4) {
            s0 += pC[((size_t)((c + 0) * 32 + b)) * 256 + j];
            s1 += pC[((size_t)((c + 1) * 32 + b)) * 256 + j];
            s2 += pC[((size_t)((c + 2) * 32 + b)) * 256 + j];
            s3 += pC[((size_t)((c + 3) * 32 + b)) * 256 + j];
        }
        Cst[b * 256 + j] = s0 + s1 + s2 + s3;
    }
}

// ---------------- init: zero awf2 (both parities) + zsum2 ----------------
__global__ __launch_bounds__(256) void k_init2(float* __restrict__ awf2, float* __restrict__ zsum2) {
    int i0 = blockIdx.x * 256 + threadIdx.x;
    for (int i = i0; i < 16384; i += 1024) awf2[i] = 0.f;
    if (i0 < 64) zsum2[i0] = 0.f;
}

// ---------------- W_fc [256][10000] f32 -> wfcT16 [10000][256] bf16 (optional) ----------------
__global__ __launch_bounds__(256) void k_wfc16(const float* __restrict__ W_fc,
                                               unsigned short* __restrict__ wfcT16) {
    __shared__ unsigned short tile[16 * 256];
    int tid = threadIdx.x;
    int c0 = blockIdx.x * 16;
    for (int p = 0; p < 16; ++p) {
        int r = p * 16 + (tid >> 4);
        int c = tid & 15;
        tile[c * 256 + r] = f2bf(W_fc[(size_t)r * Vz + c0 + c]);
    }
    __syncthreads();
    unsigned int* dst = (unsigned int*)wfcT16 + (size_t)c0 * 128;
    const unsigned int* src = (const unsigned int*)tile;
    for (int i = tid; i < 2048; i += 256) dst[i] = src[i];
}

// ---------------- 5 gate weights [1024][256] f32 -> wg16 [5][256][1024] bf16 ----------------
__global__ __launch_bounds__(256) void k_wg16(const float* __restrict__ W_i, const float* __restrict__ W_f,
                                              const float* __restrict__ W_o, const float* __restrict__ W_g1,
                                              const float* __restrict__ W_g2,
                                              unsigned short* __restrict__ wg16) {
    __shared__ unsigned short tile[16 * 1024];
    int tid = threadIdx.x;
    int g = blockIdx.x >> 4;
    int c0 = (blockIdx.x & 15) * 16;
    const float* Wg = (g == 0) ? W_i : (g == 1) ? W_f : (g == 2) ? W_o : (g == 3) ? W_g1 : W_g2;
    for (int p = 0; p < 64; ++p) {
        int r = p * 16 + (tid >> 4);
        int c = tid & 15;
        tile[c * 1024 + r] = f2bf(Wg[(size_t)r * 256 + c0 + c]);
    }
    __syncthreads();
    unsigned int* dst = (unsigned int*)wg16 + ((size_t)(g * 256 + c0)) * 512;
    const unsigned int* src = (const unsigned int*)tile;
    for (int i = tid; i < 8192; i += 256) dst[i] = src[i];
}

// ---------------- att1h = bf16(info@W_enc+b_enc); infoh = bf16(info_sorted) ----------------
__global__ __launch_bounds__(256) void k_att1(const float* __restrict__ info, const int* __restrict__ ord,
                                              const float* __restrict__ W, const float* __restrict__ bias,
                                              unsigned short* __restrict__ att1h,
                                              unsigned short* __restrict__ infoh) {
    __shared__ __align__(16) float xsT[256 * 36];
    int tid = threadIdx.x;
    int r0 = blockIdx.x * 32;
    int b = r0 >> 10, p0 = r0 & 1023;
    const float* src = info + (size_t)ord[b] * INFLAT + (size_t)p0 * 256;
    for (int idx = tid; idx < 2048; idx += 256) {
        int r = idx >> 6, kq = idx & 63;
        float4 v = *(const float4*)&src[r * 256 + kq * 4];
        xsT[(kq * 4 + 0) * 36 + r] = v.x;
        xsT[(kq * 4 + 1) * 36 + r] = v.y;
        xsT[(kq * 4 + 2) * 36 + r] = v.z;
        xsT[(kq * 4 + 3) * 36 + r] = v.w;
    }
    __syncthreads();
#pragma unroll 4
    for (int r = 0; r < 32; ++r)
        infoh[(size_t)(r0 + r) * 256 + tid] = f2bf(xsT[tid * 36 + r]);
    float acc[32];
#pragma unroll
    for (int r = 0; r < 32; ++r) acc[r] = 0.f;
    for (int k = 0; k < 256; ++k) {
        float w = W[k * 256 + tid];
        const float4* xr = (const float4*)&xsT[k * 36];
#pragma unroll
        for (int rq = 0; rq < 8; ++rq) {
            float4 x4 = xr[rq];
            acc[rq * 4 + 0] += x4.x * w;
            acc[rq * 4 + 1] += x4.y * w;
            acc[rq * 4 + 2] += x4.z * w;
            acc[rq * 4 + 3] += x4.w * w;
        }
    }
    float bj = bias[tid];
#pragma unroll
    for (int r = 0; r < 32; ++r)
        att1h[(size_t)(r0 + r) * 256 + tid] = f2bf(acc[r] + bj);
}

// ---------------- fused steps kernel (2 barriers/step) ----------------
struct KArgs {
    const float *emb, *W_dec, *b_dec, *W_full, *b_full;
    const float *b_i, *b_f, *b_o, *b_g1, *b_g2;
    const float *W_mlp, *b_mlp, *W_fc, *b_fc;
    const int *caps;
    const unsigned short *att1h, *infoh, *wfcT16, *wg16;   // wfcT16 may be null
    const float *h0, *c0, *C0;
    float *expe, *zsum2, *awf2, *gsp, *hst;
    const int *ord, *slp;
    int *root, *slots;
    float *out_pred, *out_alpha;
};

// pred: transposed-bf16 path if wfcT16 != null, else f32 strided path
__device__ void pred_task2(const KArgs& a, unsigned short* hb, int tile, int tm1) {
    int tid = threadIdx.x;
    for (int i = tid; i < 8192; i += 256) hb[i] = f2bf(agload(&a.hst[i]));
    __syncthreads();
    int col = tile * 64 + (tid & 63), bg = tid >> 6;
    if (col >= Vz) return;
    float acc[8] = {0.f, 0.f, 0.f, 0.f, 0.f, 0.f, 0.f, 0.f};
    if (a.wfcT16) {
        const uint4* wcol = (const uint4*)(a.wfcT16 + (size_t)col * 256);
#pragma unroll 4
        for (int q = 0; q < 32; ++q) {
            uint4 u = wcol[q];
            float w0 = bfl(u.x), w1 = bfh(u.x), w2 = bfl(u.y), w3 = bfh(u.y);
            float w4 = bfl(u.z), w5 = bfh(u.z), w6 = bfl(u.w), w7 = bfh(u.w);
#pragma unroll
            for (int bi = 0; bi < 8; ++bi) {
                uint4 hv = *(const uint4*)&hb[(bg * 8 + bi) * 256 + q * 8];
                acc[bi] += bfl(hv.x) * w0 + bfh(hv.x) * w1 + bfl(hv.y) * w2 + bfh(hv.y) * w3
                         + bfl(hv.z) * w4 + bfh(hv.z) * w5 + bfl(hv.w) * w6 + bfh(hv.w) * w7;
            }
        }
    } else {
        for (int jq = 0; jq < 64; ++jq) {
            float w0 = a.W_fc[(size_t)(jq * 4 + 0) * Vz + col];
            float w1 = a.W_fc[(size_t)(jq * 4 + 1) * Vz + col];
            float w2 = a.W_fc[(size_t)(jq * 4 + 2) * Vz + col];
            float w3 = a.W_fc[(size_t)(jq * 4 + 3) * Vz + col];
#pragma unroll
            for (int bi = 0; bi < 8; ++bi) {
                uint2 u = *(const uint2*)&hb[(bg * 8 + bi) * 256 + jq * 4];
                acc[bi] += bfl(u.x) * w0 + bfh(u.x) * w1 + bfl(u.y) * w2 + bfh(u.y) * w3;
            }
        }
    }
    float bv = a.b_fc[col];
#pragma unroll
    for (int bi = 0; bi < 8; ++bi) {
        int b = bg * 8 + bi;
        float r = (a.slp[b] > tm1) ? (acc[bi] + bv) : 0.f;
        a.out_pred[((size_t)b * TMz + tm1) * Vz + col] = r;
    }
}

// compute cell+mlp -> h (redundant per block; cs_r/Cs_r per-thread registers)
__device__ float cell_h(const KArgs& a, float* F, int b, float& cs_r, float& Cs_r) {
    int tid = threadIdx.x;
    float gs[5];
#pragma unroll
    for (int g = 0; g < 5; ++g) {
        float s = 0.f;
#pragma unroll
        for (int kc = 0; kc < 4; ++kc)
            s += agload(&a.gsp[((size_t)((g * 4 + kc) * 32 + b)) * 256 + tid]);
        gs[g] = s;
    }
    gs[0] += a.b_i[tid]; gs[1] += a.b_f[tid]; gs[2] += a.b_o[tid];
    gs[3] += a.b_g1[tid]; gs[4] += a.b_g2[tid];
    float iv = sigm(gs[0]), fv = sigm(gs[1]), ov = sigm(gs[2]);
    float g1 = tanhf(gs[3]), g2 = tanhf(gs[4]);
    cs_r = fv * cs_r + iv * g1;
    Cs_r = fv * Cs_r + iv * g2;
    F[tid] = cs_r;
    F[256 + tid] = Cs_r;
    __syncthreads();
    float m0 = a.b_mlp[tid], m1 = 0.f, m2 = 0.f, m3 = 0.f;
    const float* wm = a.W_mlp + tid;
    for (int k = 0; k < 512; k += 4) {
        m0 += F[k + 0] * wm[(size_t)(k + 0) * 256];
        m1 += F[k + 1] * wm[(size_t)(k + 1) * 256];
        m2 += F[k + 2] * wm[(size_t)(k + 2) * 256];
        m3 += F[k + 3] * wm[(size_t)(k + 3) * 256];
    }
    __syncthreads();    // mlp reads of F done before caller overwrites
    return ov * tanhf((m0 + m1) + (m2 + m3));
}

// LDS (80 KB): [0..32767] attB (swizzled), [32768..65535] infB, [65536..81919] scratch F/S16
__global__ __launch_bounds__(256, 2) void k_steps(KArgs a) {
    __shared__ __align__(16) unsigned char smem[81920];
    unsigned char* attB = smem;
    unsigned char* infB = smem + 32768;
    float* F = (float*)(smem + 65536);
    unsigned short* S16 = (unsigned short*)(smem + 65536);

    int bid = blockIdx.x, tid = threadIdx.x;
    int b = bid >> 4, sub = bid & 15;
    int gen = 0;

    // persistent staging of this block's att1h/infoh slice (once)
    {
        const unsigned short* ag = a.att1h + (size_t)(b * 1024 + sub * 64) * 256;
        const unsigned short* ig = a.infoh + (size_t)(b * 1024 + sub * 64) * 256;
        for (int idx = tid; idx < 2048; idx += 256) {
            int r = idx >> 5, qc = idx & 31;
            uint4 v = *(const uint4*)(ag + (size_t)r * 256 + qc * 8);
            *(uint4*)(attB + r * 512 + ((qc ^ (r & 7)) << 4)) = v;
            uint4 w2 = *(const uint4*)(ig + (size_t)r * 256 + qc * 8);
            *(uint4*)(infB + idx * 16) = w2;
        }
    }
    __syncthreads();

    float cs_r = a.c0[b * 256 + tid];
    float Cs_r = a.C0[b * 256 + tid];

    for (int t = 0; t < TMz; ++t) {
        // ---------- PA: [cell+mlp+h (t>0)] + at2 + e + expe + zsum + awf ----------
        {
            float hv;
            if (t == 0) {
                hv = a.h0[b * 256 + tid];
            } else {
                hv = cell_h(a, F, b, cs_r, Cs_r);
            }
            if (sub == 0) agstore(&a.hst[b * 256 + tid], hv);
            F[512 + tid] = hv;
            __syncthreads();
            // at2 = h @ W_dec + b_dec
            {
                float s0 = a.b_dec[tid], s1 = 0.f, s2 = 0.f, s3 = 0.f;
                const float* wd = a.W_dec + tid;
                for (int k = 0; k < 256; k += 4) {
                    s0 += F[512 + k + 0] * wd[(size_t)(k + 0) * 256];
                    s1 += F[512 + k + 1] * wd[(size_t)(k + 1) * 256];
                    s2 += F[512 + k + 2] * wd[(size_t)(k + 2) * 256];
                    s3 += F[512 + k + 3] * wd[(size_t)(k + 3) * 256];
                }
                float at2v = (s0 + s1) + (s2 + s3);
                __syncthreads();        // everyone done reading F[512..767] (h)
                F[tid] = at2v;
                F[256 + tid] = a.W_full[tid];
            }
            __syncthreads();
            int pl = tid & 63, kq = tid >> 6;
            float part = 0.f;
#pragma unroll
            for (int q = 0; q < 8; ++q) {
                int c = kq * 8 + q;
                uint4 u = *(const uint4*)(attB + pl * 512 + ((c ^ (pl & 7)) << 4));
                const float* A = F + kq * 64 + q * 8;
                const float* W = F + 256 + kq * 64 + q * 8;
                part += fmaxf(bfl(u.x) + A[0], 0.f) * W[0];
                part += fmaxf(bfh(u.x) + A[1], 0.f) * W[1];
                part += fmaxf(bfl(u.y) + A[2], 0.f) * W[2];
                part += fmaxf(bfh(u.y) + A[3], 0.f) * W[3];
                part += fmaxf(bfl(u.z) + A[4], 0.f) * W[4];
                part += fmaxf(bfh(u.z) + A[5], 0.f) * W[5];
                part += fmaxf(bfl(u.w) + A[6], 0.f) * W[6];
                part += fmaxf(bfh(u.w) + A[7], 0.f) * W[7];
            }
            F[512 + kq * 64 + pl] = part;
            __syncthreads();
            if (tid < 64) {
                float e = F[512 + tid] + F[576 + tid] + F[640 + tid] + F[704 + tid] + a.b_full[0];
                float ex = expf(e);
                agstore(&a.expe[b * 1024 + sub * 64 + tid], ex);
                F[768 + tid] = ex;
                float s = ex;
                s += __shfl_down(s, 32); s += __shfl_down(s, 16); s += __shfl_down(s, 8);
                s += __shfl_down(s, 4);  s += __shfl_down(s, 2);  s += __shfl_down(s, 1);
                if (tid == 0) agadd(&a.zsum2[(t & 1) * 32 + b], s);
            }
            __syncthreads();
            int gg = tid >> 7, c2 = tid & 127;
            const unsigned char* ib = infB + gg * 512 + c2 * 4;
            const float* ex = F + 768;
            float a0 = 0.f, a1 = 0.f;
#pragma unroll
            for (int i = 0; i < 32; ++i) {
                unsigned int u = *(const unsigned int*)(ib + i * 1024);
                float ev = ex[i * 2 + gg];
                a0 += ev * bfl(u);
                a1 += ev * bfh(u);
            }
            F[832 + gg * 256 + c2 * 2]     = a0;
            F[832 + gg * 256 + c2 * 2 + 1] = a1;
            __syncthreads();
            agadd(&a.awf2[(t & 1) * 8192 + b * 256 + tid], F[832 + tid] + F[1088 + tid]);
        }
        gbar(a.slots, a.root, ++gen);

        // ---------- PB: gates(0..79) | pred+alpha+zeroing(80..236) ----------
        if (bid < 80) {
            int g = bid / 16, s16 = bid % 16;
            int ct = s16 >> 2, kc = s16 & 3;
            for (int idx = tid; idx < 8192; idx += 256) {
                int b2 = idx >> 8, kk = idx & 255;
                float v;
                if (kc == 0) {
                    int cap = a.caps[a.ord[b2] * Tz + t];
                    v = a.emb[(size_t)cap * 512 + kk];
                } else if (kc == 1) {
                    int cap = a.caps[a.ord[b2] * Tz + t];
                    v = a.emb[(size_t)cap * 512 + 256 + kk];
                } else if (kc == 2) {
                    v = agload(&a.awf2[(t & 1) * 8192 + b2 * 256 + kk]);   // raw, scaled after GEMV
                } else {
                    v = agload(&a.hst[b2 * 256 + kk]);
                }
                S16[idx] = f2bf(v);
            }
            __syncthreads();
            int col = ct * 64 + (tid & 63), bg = tid >> 6;
            const uint4* wcol = (const uint4*)(a.wg16 + ((size_t)(g * 256 + col)) * 1024 + kc * 256);
            float acc[8] = {0.f,0.f,0.f,0.f,0.f,0.f,0.f,0.f};
#pragma unroll 4
            for (int q = 0; q < 32; ++q) {
                uint4 u = wcol[q];
                float w0 = bfl(u.x), w1 = bfh(u.x), w2 = bfl(u.y), w3 = bfh(u.y);
                float w4 = bfl(u.z), w5 = bfh(u.z), w6 = bfl(u.w), w7 = bfh(u.w);
#pragma unroll
                for (int bi = 0; bi < 8; ++bi) {
                    uint4 xv = *(const uint4*)&S16[(bg * 8 + bi) * 256 + q * 8];
                    acc[bi] += bfl(xv.x) * w0 + bfh(xv.x) * w1 + bfl(xv.y) * w2 + bfh(xv.y) * w3
                             + bfl(xv.z) * w4 + bfh(xv.z) * w5 + bfl(xv.w) * w6 + bfh(xv.w) * w7;
                }
            }
            if (kc == 2) {
#pragma unroll
                for (int bi = 0; bi < 8; ++bi) {
                    float Z = agload(&a.zsum2[(t & 1) * 32 + bg * 8 + bi]);
                    acc[bi] *= (1.0f / Z);
                }
            }
#pragma unroll
            for (int bi = 0; bi < 8; ++bi)
                agstore(&a.gsp[((size_t)((g * 4 + kc) * 32 + bg * 8 + bi)) * 256 + col], acc[bi]);
        } else if (bid < 237) {
            if (bid < 112) {
                int bb = bid - 80;
                float Z = agload(&a.zsum2[(t & 1) * 32 + bb]);
                float invZ = 1.0f / Z;
                float am = (a.slp[bb] > t) ? invZ : 0.f;
                float* oal = a.out_alpha + ((size_t)bb * TMz + t) * 1024;
                for (int p = tid; p < 1024; p += 256) oal[p] = agload(&a.expe[bb * 1024 + p]) * am;
                // zero next-parity accumulators (last read 2 barriers ago)
                agstore(&a.awf2[((t + 1) & 1) * 8192 + bb * 256 + tid], 0.f);
                if (tid == 0) agstore(&a.zsum2[((t + 1) & 1) * 32 + bb], 0.f);
            }
            if (t > 0) pred_task2(a, S16, bid - 80, t - 1);
        }
        gbar(a.slots, a.root, ++gen);
    }

    // epilogue: h_T from gsp of t=18, then pred(18)
    {
        float hv = cell_h(a, F, b, cs_r, Cs_r);
        if (sub == 0) agstore(&a.hst[b * 256 + tid], hv);
    }
    gbar(a.slots, a.root, ++gen);
    if (bid >= 80 && bid < 237) pred_task2(a, S16, bid - 80, TMz - 1);
}

extern "C" void kernel_launch(void* const* d_in, const int* in_sizes, int n_in,
                              void* d_out, int out_size, void* d_ws, size_t ws_size,
                              hipStream_t stream) {
    const float* info  = (const float*)d_in[0];
    const float* rel   = (const float*)d_in[1];
    const int*   caps  = (const int*)d_in[2];
    const int*   lens  = (const int*)d_in[3];
    const float* emb   = (const float*)d_in[4];
    const float* W_enc = (const float*)d_in[5];
    const float* b_enc = (const float*)d_in[6];
    const float* W_dec = (const float*)d_in[7];
    const float* b_dec = (const float*)d_in[8];
    const float* W_full= (const float*)d_in[9];
    const float* b_full= (const float*)d_in[10];
    const float* W_i   = (const float*)d_in[11];
    const float* b_i   = (const float*)d_in[12];
    const float* W_f   = (const float*)d_in[13];
    const float* b_f   = (const float*)d_in[14];
    const float* W_o   = (const float*)d_in[15];
    const float* b_o   = (const float*)d_in[16];
    const float* W_g1  = (const float*)d_in[17];
    const float* b_g1  = (const float*)d_in[18];
    const float* W_g2  = (const float*)d_in[19];
    const float* b_g2  = (const float*)d_in[20];
    const float* W_mlp = (const float*)d_in[21];
    const float* b_mlp = (const float*)d_in[22];
    const float* W_fc  = (const float*)d_in[25];
    const float* b_fc  = (const float*)d_in[26];
    const float* W_ih  = (const float*)d_in[27];
    const float* b_ih  = (const float*)d_in[28];
    const float* W_ic  = (const float*)d_in[29];
    const float* b_ic  = (const float*)d_in[30];
    const float* W_iC  = (const float*)d_in[31];
    const float* b_iC  = (const float*)d_in[32];

    float* out = (float*)d_out;
    float* out_pred  = out;
    float* out_alpha = out + (size_t)Bz * TMz * Vz;
    float* out_order = out_alpha + (size_t)Bz * TMz * 1024;

    float* w = (float*)d_ws;
    float* ph   = w + WS_PH;
    float* pcp  = w + WS_PC;
    unsigned short* att1h = (unsigned short*)(w + WS_ATT1H);
    unsigned short* infoh = (unsigned short*)(w + WS_INFOH);
    float* expe = w + WS_EXPE;
    float* gsp  = w + WS_GSP;
    float* hst  = w + WS_HST;
    float* cst0 = w + WS_CST0;
    float* Cst0 = w + WS_CSTB0;
    float* awf2 = w + WS_AWF2;
    float* zsum2= w + WS_ZSUM2;
    int*   ordp = (int*)(w + WS_INTS);
    int*   slp  = ordp + 32;
    int*   barmem = ordp + 64;
    float* pC   = w + WS_PCHC;
    unsigned short* wg16   = (unsigned short*)(w + WS_WG16);
    unsigned short* wfcT16 = (unsigned short*)(w + WS_WFC16);

    int useWfc = (ws_size >= (size_t)WS_END_WFC * 4);

    k_sort<<<1, 64, 0, stream>>>(lens, out_order, ordp, slp, barmem);
    k_gemv2<<<512, 256, 0, stream>>>(info, ordp, W_ih, W_ic, ph, pcp);
    k_gemvC<<<128, 256, 0, stream>>>(rel, ordp, W_iC, pC);
    k_reduce3<<<96, 256, 0, stream>>>(ph, pcp, pC, b_ih, b_ic, b_iC, hst, cst0, Cst0);
    k_init2<<<4, 256, 0, stream>>>(awf2, zsum2);
    k_wg16<<<80, 256, 0, stream>>>(W_i, W_f, W_o, W_g1, W_g2, wg16);   // after k_reduce3 (pC dead)
    if (useWfc) k_wfc16<<<625, 256, 0, stream>>>(W_fc, wfcT16);
    k_att1<<<1024, 256, 0, stream>>>(info, ordp, W_enc, b_enc, att1h, infoh);

    KArgs ka;
    ka.emb = emb; ka.W_dec = W_dec; ka.b_dec = b_dec;
    ka.W_full = W_full; ka.b_full = b_full;
    ka.b_i = b_i; ka.b_f = b_f; ka.b_o = b_o; ka.b_g1 = b_g1; ka.b_g2 = b_g2;
    ka.W_mlp = W_mlp; ka.b_mlp = b_mlp; ka.W_fc = W_fc; ka.b_fc = b_fc;
    ka.caps = caps;
    ka.att1h = att1h; ka.infoh = infoh;
    ka.wfcT16 = useWfc ? wfcT16 : (const unsigned short*)0;
    ka.wg16 = wg16;
    ka.h0 = hst; ka.c0 = cst0; ka.C0 = Cst0;
    ka.expe = expe; ka.zsum2 = zsum2; ka.awf2 = awf2;
    ka.gsp = gsp; ka.hst = hst;
    ka.ord = ordp; ka.slp = slp;
    ka.root = barmem; ka.slots = barmem + 64;
    ka.out_pred = out_pred; ka.out_alpha = out_alpha;

    k_steps<<<NBLK, 256, 0, stream>>>(ka);
}

// Round 20
// 1948.877 us; speedup vs baseline: 2.1817x; 2.0205x over previous
//
#include <hip/hip_runtime.h>
#include <math.h>

#define Bz 32
#define Tz 20
#define TMz 19
#define Vz 10000
#define INFLAT 262144   // P*D
#define RELSZ 16384
#define NBLK 512

// workspace float offsets
#define WS_PH     0
#define WS_PC     4194304
#define WS_ATT1H  0              // bf16[32*1024*256] = 4,194,304 floats (reuses ph after k_reduce3)
#define WS_INFOH  4194304        // bf16[32*1024*256] = 4,194,304 floats (reuses pc after k_reduce3)
#define WS_EXPE   8388608        // 32768
#define WS_ZSUM   8421376        // 32 (atomic-accumulated)
#define WS_AWF    8421888        // 8192 (atomic-accumulated, unnormalized)
#define WS_GSP    8430080        // 5*4*32*256 = 163840
#define WS_HST    8593920
#define WS_CST0   8602112
#define WS_CSTB0  8610304
#define WS_CST1   8618496
#define WS_CSTB1  8626688
#define WS_AT2P   8634880        // 8*32*256 = 65536
#define WS_INTS   8700416        // ordp[32] slp[32] barmem[64+512]
#define WS_PCHC   8701440        // pC partials 128*32*256 = 1048576 (dead after k_reduce3)
#define WS_WG16   8701440        // bf16[5*256*1024] = 655,360 floats  (reuses pC region)
#define WS_WFC16  9750016        // bf16[10000*256] = 1,280,000 floats (optional, needs ws >= 44.1MB)
#define WS_END_WFC (9750016 + 1280000)

__device__ __forceinline__ float sigm(float x) { return 1.0f / (1.0f + expf(-x)); }

__device__ __forceinline__ unsigned short f2bf(float f) {
    unsigned int x = __float_as_uint(f);
    unsigned int r = (x + 0x7fffu + ((x >> 16) & 1u)) >> 16;
    return (unsigned short)r;
}
__device__ __forceinline__ float bfl(unsigned int u) { return __uint_as_float(u << 16); }
__device__ __forceinline__ float bfh(unsigned int u) { return __uint_as_float(u & 0xffff0000u); }

// Agent-scope accessors for cross-block-communicated state ONLY.
__device__ __forceinline__ float agload(const float* p) {
    return __hip_atomic_load(p, __ATOMIC_RELAXED, __HIP_MEMORY_SCOPE_AGENT);
}
__device__ __forceinline__ void agstore(float* p, float v) {
    __hip_atomic_store(p, v, __ATOMIC_RELAXED, __HIP_MEMORY_SCOPE_AGENT);
}
__device__ __forceinline__ int agloadi(const int* p) {
    return __hip_atomic_load(p, __ATOMIC_RELAXED, __HIP_MEMORY_SCOPE_AGENT);
}
__device__ __forceinline__ void agstorei(int* p, int v) {
    __hip_atomic_store(p, v, __ATOMIC_RELAXED, __HIP_MEMORY_SCOPE_AGENT);
}
__device__ __forceinline__ void agadd(float* p, float v) {
    __hip_atomic_fetch_add(p, v, __ATOMIC_RELAXED, __HIP_MEMORY_SCOPE_AGENT);
}

// Fence-free slot grid barrier (no cache invalidation).
__device__ __forceinline__ void gbar(int* slots, int* root, int gen) {
    asm volatile("s_waitcnt vmcnt(0)" ::: "memory");
    __syncthreads();
    if (blockIdx.x == 0) {
        int i0 = threadIdx.x, i1 = threadIdx.x + 256;
        if (i0 != 0) {
            while (agloadi(&slots[i0]) < gen) __builtin_amdgcn_s_sleep(1);
        }
        while (agloadi(&slots[i1]) < gen) __builtin_amdgcn_s_sleep(1);
        __syncthreads();
        if (threadIdx.x == 0) agstorei(root, gen);
    } else if (threadIdx.x == 0) {
        agstorei(&slots[blockIdx.x], gen);
        while (agloadi(root) < gen) __builtin_amdgcn_s_sleep(2);
    }
    __syncthreads();
    asm volatile("" ::: "memory");
}

// ---------------- sort + barrier init ----------------
__global__ void k_sort(const int* __restrict__ lens, float* __restrict__ out_order,
                       int* __restrict__ ord, int* __restrict__ sentlen, int* __restrict__ barmem) {
    if (threadIdx.x == 0 && blockIdx.x == 0) {
        for (int i = 0; i < 64 + NBLK; ++i) barmem[i] = 0;
        int l[Bz]; bool used[Bz];
        for (int b = 0; b < Bz; ++b) { l[b] = lens[b]; used[b] = false; }
        for (int i = 0; i < Bz; ++i) {
            int best = -1;
            for (int j = 0; j < Bz; ++j)
                if (!used[j] && (best < 0 || l[j] > l[best])) best = j;
            used[best] = true;
            ord[i] = best;
            sentlen[i] = l[best] - 1;
            out_order[i] = (float)best;
        }
    }
}

// ---------------- h0,c0: flat(32,262144) @ W_ih / W_ic (register-staged weights) ----------------
__global__ __launch_bounds__(256) void k_gemv2(const float* __restrict__ X, const int* __restrict__ ord,
                                               const float* __restrict__ W1, const float* __restrict__ W2,
                                               float* __restrict__ p1, float* __restrict__ p2) {
    __shared__ __align__(16) float xsT[512 * 36];   // 73.7 KB: [k][b], pad 36 (16B-aligned rows)
    __shared__ int ords[32];
    int tid = threadIdx.x;
    size_t k0 = (size_t)blockIdx.x * 512;

    if (tid < 32) ords[tid] = ord[tid];
    __syncthreads();

    // stage all 512 k-rows x 32 batches of x
    for (int idx = tid; idx < 4096; idx += 256) {
        int b = idx >> 7, kq = idx & 127;
        float4 v = *(const float4*)&X[(size_t)ords[b] * INFLAT + k0 + kq * 4];
        xsT[(kq * 4 + 0) * 36 + b] = v.x;
        xsT[(kq * 4 + 1) * 36 + b] = v.y;
        xsT[(kq * 4 + 2) * 36 + b] = v.z;
        xsT[(kq * 4 + 3) * 36 + b] = v.w;
    }
    __syncthreads();

    float ah[32], ac[32];
#pragma unroll
    for (int b = 0; b < 32; ++b) { ah[b] = 0.f; ac[b] = 0.f; }

    const float* w1p = W1 + k0 * 256 + tid;
    const float* w2p = W2 + k0 * 256 + tid;
#pragma unroll 4
    for (int k = 0; k < 512; ++k) {
        float w1 = w1p[(size_t)k * 256];
        float w2 = w2p[(size_t)k * 256];
        const float4* xr = (const float4*)&xsT[k * 36];
#pragma unroll
        for (int bq = 0; bq < 8; ++bq) {
            float4 x4 = xr[bq];
            ah[bq * 4 + 0] += x4.x * w1; ac[bq * 4 + 0] += x4.x * w2;
            ah[bq * 4 + 1] += x4.y * w1; ac[bq * 4 + 1] += x4.y * w2;
            ah[bq * 4 + 2] += x4.z * w1; ac[bq * 4 + 2] += x4.z * w2;
            ah[bq * 4 + 3] += x4.w * w1; ac[bq * 4 + 3] += x4.w * w2;
        }
    }
#pragma unroll
    for (int b = 0; b < 32; ++b) {
        size_t o = ((size_t)blockIdx.x * 32 + b) * 256 + tid;
        p1[o] = ah[b];
        p2[o] = ac[b];
    }
}

// ---------------- C0: rel(32,16384) @ W_iC, split-K ----------------
__global__ __launch_bounds__(256) void k_gemvC(const float* __restrict__ R, const int* __restrict__ ord,
                                               const float* __restrict__ W, float* __restrict__ p) {
    __shared__ float xs[32 * 128];
    __shared__ int ords[32];
    int tid = threadIdx.x, bx = blockIdx.x;
    if (tid < 32) ords[tid] = ord[tid];
    __syncthreads();
    int k0 = bx * 128;
    for (int idx = tid; idx < 32 * 128; idx += 256) {
        int b = idx >> 7, kk = idx & 127;
        xs[idx] = R[(size_t)ords[b] * RELSZ + k0 + kk];
    }
    __syncthreads();
    float acc[32];
#pragma unroll
    for (int b = 0; b < 32; ++b) acc[b] = 0.f;
    for (int kk = 0; kk < 128; ++kk) {
        float w = W[(size_t)(k0 + kk) * 256 + tid];
#pragma unroll
        for (int b = 0; b < 32; ++b) acc[b] += xs[b * 128 + kk] * w;
    }
#pragma unroll
    for (int b = 0; b < 32; ++b) p[((size_t)bx * 32 + b) * 256 + tid] = acc[b];
}

// ---------------- combined split-K reduces: h0, c0, C0 ----------------
__global__ __launch_bounds__(256) void k_reduce3(const float* __restrict__ ph, const float* __restrict__ pc,
                                                 const float* __restrict__ pC,
                                                 const float* __restrict__ b_ih, const float* __restrict__ b_ic,
                                                 const float* __restrict__ b_iC,
                                                 float* __restrict__ hst, float* __restrict__ cst,
                                                 float* __restrict__ Cst) {
    int which = blockIdx.x >> 5, b = blockIdx.x & 31, j = threadIdx.x;
    if (which == 0) {
        float s0 = b_ih[j], s1 = 0.f, s2 = 0.f, s3 = 0.f;
        for (int c = 0; c < 512; c += 4) {
            s0 += ph[((size_t)((c + 0) * 32 + b)) * 256 + j];
            s1 += ph[((size_t)((c + 1) * 32 + b)) * 256 + j];
            s2 += ph[((size_t)((c + 2) * 32 + b)) * 256 + j];
            s3 += ph[((size_t)((c + 3) * 32 + b)) * 256 + j];
        }
        hst[b * 256 + j] = s0 + s1 + s2 + s3;
    } else if (which == 1) {
        float s0 = b_ic[j], s1 = 0.f, s2 = 0.f, s3 = 0.f;
        for (int c = 0; c < 512; c += 4) {
            s0 += pc[((size_t)((c + 0) * 32 + b)) * 256 + j];
            s1 += pc[((size_t)((c + 1) * 32 + b)) * 256 + j];
            s2 += pc[((size_t)((c + 2) * 32 + b)) * 256 + j];
            s3 += pc[((size_t)((c + 3) * 32 + b)) * 256 + j];
        }
        cst[b * 256 + j] = s0 + s1 + s2 + s3;
    } else {
        float s0 = b_iC[j], s1 = 0.f, s2 = 0.f, s3 = 0.f;
        for (int c = 0; c < 128; c += 4) {
            s0 += pC[((size_t)((c + 0) * 32 + b)) * 256 + j];
            s1 += pC[((size_t)((c + 1) * 32 + b)) * 256 + j];
            s2 += pC[((size_t)((c + 2) * 32 + b)) * 256 + j];
            s3 += pC[((size_t)((c + 3) * 32 + b)) * 256 + j];
        }
        Cst[b * 256 + j] = s0 + s1 + s2 + s3;
    }
}

// ---------------- init: at2p slot0 = h0 @ W_dec, zero rest + awf + zsum ----------------
__global__ __launch_bounds__(256) void k_init2(const float* __restrict__ hst, const float* __restrict__ W_dec,
                                               float* __restrict__ at2p, float* __restrict__ awf,
                                               float* __restrict__ zsum) {
    __shared__ __align__(16) float hs[8192];
    int tid = threadIdx.x;
    for (int i = blockIdx.x * 256 + tid; i < 8192; i += 1024) awf[i] = 0.f;
    if (blockIdx.x == 0 && tid < 32) zsum[tid] = 0.f;
    for (int i = tid; i < 2048; i += 256) ((float4*)hs)[i] = ((const float4*)hst)[i];
    __syncthreads();
    int col = blockIdx.x * 64 + (tid & 63), bg = tid >> 6;
    float acc[8] = {0.f,0.f,0.f,0.f,0.f,0.f,0.f,0.f};
    for (int k = 0; k < 256; ++k) {
        float w = W_dec[(size_t)k * 256 + col];
#pragma unroll
        for (int bi = 0; bi < 8; ++bi) acc[bi] += hs[(bg * 8 + bi) * 256 + k] * w;
    }
#pragma unroll
    for (int bi = 0; bi < 8; ++bi) {
        int b = bg * 8 + bi;
        at2p[((size_t)(b * 8 + 0)) * 256 + col] = acc[bi];
#pragma unroll
        for (int ct = 1; ct < 8; ++ct) at2p[((size_t)(b * 8 + ct)) * 256 + col] = 0.f;
    }
}

// ---------------- W_fc [256][10000] f32 -> wfcT16 [10000][256] bf16 (optional) ----------------
__global__ __launch_bounds__(256) void k_wfc16(const float* __restrict__ W_fc,
                                               unsigned short* __restrict__ wfcT16) {
    __shared__ unsigned short tile[16 * 256];
    int tid = threadIdx.x;
    int c0 = blockIdx.x * 16;
    for (int p = 0; p < 16; ++p) {
        int r = p * 16 + (tid >> 4);
        int c = tid & 15;
        tile[c * 256 + r] = f2bf(W_fc[(size_t)r * Vz + c0 + c]);
    }
    __syncthreads();
    unsigned int* dst = (unsigned int*)wfcT16 + (size_t)c0 * 128;
    const unsigned int* src = (const unsigned int*)tile;
    for (int i = tid; i < 2048; i += 256) dst[i] = src[i];
}

// ---------------- 5 gate weights [1024][256] f32 -> wg16 [5][256][1024] bf16 ----------------
__global__ __launch_bounds__(256) void k_wg16(const float* __restrict__ W_i, const float* __restrict__ W_f,
                                              const float* __restrict__ W_o, const float* __restrict__ W_g1,
                                              const float* __restrict__ W_g2,
                                              unsigned short* __restrict__ wg16) {
    __shared__ unsigned short tile[16 * 1024];  // 32 KB
    int tid = threadIdx.x;
    int g = blockIdx.x >> 4;
    int c0 = (blockIdx.x & 15) * 16;
    const float* Wg = (g == 0) ? W_i : (g == 1) ? W_f : (g == 2) ? W_o : (g == 3) ? W_g1 : W_g2;
    for (int p = 0; p < 64; ++p) {
        int r = p * 16 + (tid >> 4);
        int c = tid & 15;
        tile[c * 1024 + r] = f2bf(Wg[(size_t)r * 256 + c0 + c]);
    }
    __syncthreads();
    unsigned int* dst = (unsigned int*)wg16 + ((size_t)(g * 256 + c0)) * 512;
    const unsigned int* src = (const unsigned int*)tile;
    for (int i = tid; i < 8192; i += 256) dst[i] = src[i];
}

// ---------------- att1h = bf16(info_sorted @ W_enc + b_enc); infoh = bf16(info_sorted) ----------------
__global__ __launch_bounds__(256) void k_att1(const float* __restrict__ info, const int* __restrict__ ord,
                                              const float* __restrict__ W, const float* __restrict__ bias,
                                              unsigned short* __restrict__ att1h,
                                              unsigned short* __restrict__ infoh) {
    __shared__ __align__(16) float xsT[256 * 36];
    int tid = threadIdx.x;
    int r0 = blockIdx.x * 32;
    int b = r0 >> 10, p0 = r0 & 1023;
    const float* src = info + (size_t)ord[b] * INFLAT + (size_t)p0 * 256;
    for (int idx = tid; idx < 2048; idx += 256) {
        int r = idx >> 6, kq = idx & 63;
        float4 v = *(const float4*)&src[r * 256 + kq * 4];
        xsT[(kq * 4 + 0) * 36 + r] = v.x;
        xsT[(kq * 4 + 1) * 36 + r] = v.y;
        xsT[(kq * 4 + 2) * 36 + r] = v.z;
        xsT[(kq * 4 + 3) * 36 + r] = v.w;
    }
    __syncthreads();
#pragma unroll 4
    for (int r = 0; r < 32; ++r)
        infoh[(size_t)(r0 + r) * 256 + tid] = f2bf(xsT[tid * 36 + r]);
    float acc[32];
#pragma unroll
    for (int r = 0; r < 32; ++r) acc[r] = 0.f;
    for (int k = 0; k < 256; ++k) {
        float w = W[k * 256 + tid];
        const float4* xr = (const float4*)&xsT[k * 36];
#pragma unroll
        for (int rq = 0; rq < 8; ++rq) {
            float4 x4 = xr[rq];
            acc[rq * 4 + 0] += x4.x * w;
            acc[rq * 4 + 1] += x4.y * w;
            acc[rq * 4 + 2] += x4.z * w;
            acc[rq * 4 + 3] += x4.w * w;
        }
    }
    float bj = bias[tid];
#pragma unroll
    for (int r = 0; r < 32; ++r)
        att1h[(size_t)(r0 + r) * 256 + tid] = f2bf(acc[r] + bj);
}

// ---------------- fused steps kernel ----------------
struct KArgs {
    const float *info, *emb, *W_dec, *b_dec, *W_full, *b_full;
    const float *b_i, *b_f, *b_o, *b_g1, *b_g2;
    const float *W_mlp, *b_mlp, *W_fc, *b_fc;
    const int *caps;
    const unsigned short *att1h, *infoh, *wfcT16, *wg16;   // wfcT16 may be null
    float *expe, *zsum, *awf, *gsp, *hst, *cst0, *Cst0, *cst1, *Cst1, *at2p;
    const int *ord, *slp;
    int *root, *slots;
    float *out_pred, *out_alpha;
};

// pred: transposed-bf16 path if wfcT16 != null, else f32 strided path
__device__ void pred_task2(const KArgs& a, unsigned short* hb, int tile, int tm1) {
    int tid = threadIdx.x;
    for (int i = tid; i < 8192; i += 256) hb[i] = f2bf(agload(&a.hst[i]));
    __syncthreads();
    int col = tile * 64 + (tid & 63), bg = tid >> 6;
    if (col >= Vz) return;
    float acc[8] = {0.f, 0.f, 0.f, 0.f, 0.f, 0.f, 0.f, 0.f};
    if (a.wfcT16) {
        const uint4* wcol = (const uint4*)(a.wfcT16 + (size_t)col * 256);
#pragma unroll 4
        for (int q = 0; q < 32; ++q) {
            uint4 u = wcol[q];
            float w0 = bfl(u.x), w1 = bfh(u.x), w2 = bfl(u.y), w3 = bfh(u.y);
            float w4 = bfl(u.z), w5 = bfh(u.z), w6 = bfl(u.w), w7 = bfh(u.w);
#pragma unroll
            for (int bi = 0; bi < 8; ++bi) {
                uint4 hv = *(const uint4*)&hb[(bg * 8 + bi) * 256 + q * 8];
                acc[bi] += bfl(hv.x) * w0 + bfh(hv.x) * w1 + bfl(hv.y) * w2 + bfh(hv.y) * w3
                         + bfl(hv.z) * w4 + bfh(hv.z) * w5 + bfl(hv.w) * w6 + bfh(hv.w) * w7;
            }
        }
    } else {
        for (int jq = 0; jq < 64; ++jq) {
            float w0 = a.W_fc[(size_t)(jq * 4 + 0) * Vz + col];
            float w1 = a.W_fc[(size_t)(jq * 4 + 1) * Vz + col];
            float w2 = a.W_fc[(size_t)(jq * 4 + 2) * Vz + col];
            float w3 = a.W_fc[(size_t)(jq * 4 + 3) * Vz + col];
#pragma unroll
            for (int bi = 0; bi < 8; ++bi) {
                uint2 u = *(const uint2*)&hb[(bg * 8 + bi) * 256 + jq * 4];
                acc[bi] += bfl(u.x) * w0 + bfh(u.x) * w1 + bfl(u.y) * w2 + bfh(u.y) * w3;
            }
        }
    }
    float bv = a.b_fc[col];
#pragma unroll
    for (int bi = 0; bi < 8; ++bi) {
        int b = bg * 8 + bi;
        float r = (a.slp[b] > tm1) ? (acc[bi] + bv) : 0.f;
        a.out_pred[((size_t)b * TMz + tm1) * Vz + col] = r;
    }
}

// LDS (80 KB): [0..32767] attB (swizzled bf16 att1h slice), [32768..65535] infB (linear bf16 info slice),
// [65536..81919] scratch union: PA floats F[0..1343]; PB x/h bf16 stage S16[0..8191]; PC floats F[0..1087]
__global__ __launch_bounds__(256, 2) void k_steps(KArgs a) {
    __shared__ __align__(16) unsigned char smem[81920];
    unsigned char* attB = smem;
    unsigned char* infB = smem + 32768;
    float* F = (float*)(smem + 65536);
    unsigned short* S16 = (unsigned short*)(smem + 65536);

    int bid = blockIdx.x, tid = threadIdx.x;
    int b = bid >> 4, sub = bid & 15;
    int gen = 0;

    // persistent staging of this block's att1h/infoh slice (once)
    {
        const unsigned short* ag = a.att1h + (size_t)(b * 1024 + sub * 64) * 256;
        const unsigned short* ig = a.infoh + (size_t)(b * 1024 + sub * 64) * 256;
        for (int idx = tid; idx < 2048; idx += 256) {
            int r = idx >> 5, qc = idx & 31;
            uint4 v = *(const uint4*)(ag + (size_t)r * 256 + qc * 8);
            *(uint4*)(attB + r * 512 + ((qc ^ (r & 7)) << 4)) = v;
            uint4 w2 = *(const uint4*)(ig + (size_t)r * 256 + qc * 8);
            *(uint4*)(infB + idx * 16) = w2;
        }
    }
    __syncthreads();

    for (int t = 0; t < TMz; ++t) {
        // ---------- PA: at2 + e + expe + zsum + awf (512 blocks, LDS-resident data) ----------
        {
            float v = a.b_dec[tid];
#pragma unroll
            for (int ct = 0; ct < 8; ++ct) v += agload(&a.at2p[((size_t)(b * 8 + ct)) * 256 + tid]);
            F[tid] = v;                 // at2
            F[256 + tid] = a.W_full[tid];
            __syncthreads();
            int pl = tid & 63, kq = tid >> 6;
            float part = 0.f;
#pragma unroll
            for (int q = 0; q < 8; ++q) {
                int c = kq * 8 + q;
                uint4 u = *(const uint4*)(attB + pl * 512 + ((c ^ (pl & 7)) << 4));
                const float* A = F + kq * 64 + q * 8;
                const float* W = F + 256 + kq * 64 + q * 8;
                part += fmaxf(bfl(u.x) + A[0], 0.f) * W[0];
                part += fmaxf(bfh(u.x) + A[1], 0.f) * W[1];
                part += fmaxf(bfl(u.y) + A[2], 0.f) * W[2];
                part += fmaxf(bfh(u.y) + A[3], 0.f) * W[3];
                part += fmaxf(bfl(u.z) + A[4], 0.f) * W[4];
                part += fmaxf(bfh(u.z) + A[5], 0.f) * W[5];
                part += fmaxf(bfl(u.w) + A[6], 0.f) * W[6];
                part += fmaxf(bfh(u.w) + A[7], 0.f) * W[7];
            }
            F[512 + kq * 64 + pl] = part;
            __syncthreads();
            if (tid < 64) {
                float e = F[512 + tid] + F[576 + tid] + F[640 + tid] + F[704 + tid] + a.b_full[0];
                float ex = expf(e);
                agstore(&a.expe[b * 1024 + sub * 64 + tid], ex);
                F[768 + tid] = ex;
                float s = ex;
                s += __shfl_down(s, 32); s += __shfl_down(s, 16); s += __shfl_down(s, 8);
                s += __shfl_down(s, 4);  s += __shfl_down(s, 2);  s += __shfl_down(s, 1);
                if (tid == 0) agadd(&a.zsum[b], s);
            }
            __syncthreads();
            int gg = tid >> 7, c2 = tid & 127;
            const unsigned char* ib = infB + gg * 512 + c2 * 4;
            const float* ex = F + 768;
            float a0 = 0.f, a1 = 0.f;
#pragma unroll
            for (int i = 0; i < 32; ++i) {
                unsigned int u = *(const unsigned int*)(ib + i * 1024);
                float ev = ex[i * 2 + gg];
                a0 += ev * bfl(u);
                a1 += ev * bfh(u);
            }
            F[832 + gg * 256 + c2 * 2]     = a0;
            F[832 + gg * 256 + c2 * 2 + 1] = a1;
            __syncthreads();
            agadd(&a.awf[b * 256 + tid], F[832 + tid] + F[1088 + tid]);
        }
        gbar(a.slots, a.root, ++gen);

        // ---------- PB: gates(0..79) | pred+alpha(80..236) ----------
        if (bid < 80) {
            int g = bid / 16, s16 = bid % 16;
            int ct = s16 >> 2, kc = s16 & 3;
            for (int idx = tid; idx < 8192; idx += 256) {
                int b2 = idx >> 8, kk = idx & 255;
                float v;
                if (kc == 0) {
                    int cap = a.caps[a.ord[b2] * Tz + t];
                    v = a.emb[(size_t)cap * 512 + kk];
                } else if (kc == 1) {
                    int cap = a.caps[a.ord[b2] * Tz + t];
                    v = a.emb[(size_t)cap * 512 + 256 + kk];
                } else if (kc == 2) {
                    v = agload(&a.awf[b2 * 256 + kk]);   // raw, scaled after GEMV
                } else {
                    v = agload(&a.hst[b2 * 256 + kk]);
                }
                S16[idx] = f2bf(v);
            }
            __syncthreads();
            int col = ct * 64 + (tid & 63), bg = tid >> 6;
            const uint4* wcol = (const uint4*)(a.wg16 + ((size_t)(g * 256 + col)) * 1024 + kc * 256);
            float acc[8] = {0.f,0.f,0.f,0.f,0.f,0.f,0.f,0.f};
#pragma unroll 4
            for (int q = 0; q < 32; ++q) {
                uint4 u = wcol[q];
                float w0 = bfl(u.x), w1 = bfh(u.x), w2 = bfl(u.y), w3 = bfh(u.y);
                float w4 = bfl(u.z), w5 = bfh(u.z), w6 = bfl(u.w), w7 = bfh(u.w);
#pragma unroll
                for (int bi = 0; bi < 8; ++bi) {
                    uint4 xv = *(const uint4*)&S16[(bg * 8 + bi) * 256 + q * 8];
                    acc[bi] += bfl(xv.x) * w0 + bfh(xv.x) * w1 + bfl(xv.y) * w2 + bfh(xv.y) * w3
                             + bfl(xv.z) * w4 + bfh(xv.z) * w5 + bfl(xv.w) * w6 + bfh(xv.w) * w7;
                }
            }
            if (kc == 2) {
#pragma unroll
                for (int bi = 0; bi < 8; ++bi) {
                    float Z = agload(&a.zsum[bg * 8 + bi]);
                    acc[bi] *= (1.0f / Z);
                }
            }
#pragma unroll
            for (int bi = 0; bi < 8; ++bi)
                agstore(&a.gsp[((size_t)((g * 4 + kc) * 32 + bg * 8 + bi)) * 256 + col], acc[bi]);
        } else if (bid < 237) {
            if (bid < 112) {
                int bb = bid - 80;
                float Z = agload(&a.zsum[bb]);
                float invZ = 1.0f / Z;
                float am = (a.slp[bb] > t) ? invZ : 0.f;
                float* oal = a.out_alpha + ((size_t)bb * TMz + t) * 1024;
                for (int p = tid; p < 1024; p += 256) oal[p] = agload(&a.expe[bb * 1024 + p]) * am;
            }
            if (t > 0) pred_task2(a, S16, bid - 80, t - 1);
        }
        gbar(a.slots, a.root, ++gen);

        // ---------- PC: cell + mlp + h + at2p + awf/zsum zero (256 blocks: b x ct8) ----------
        if (bid < 256) {
            int bb = bid >> 3, ct = bid & 7;
            int j = tid;
            const float* csOld = (t & 1) ? a.cst1 : a.cst0;
            const float* CsOld = (t & 1) ? a.Cst1 : a.Cst0;
            float* csNew = (t & 1) ? a.cst0 : a.cst1;
            float* CsNew = (t & 1) ? a.Cst0 : a.Cst1;
            float gs[5];
#pragma unroll
            for (int g = 0; g < 5; ++g) {
                float s = 0.f;
#pragma unroll
                for (int kc = 0; kc < 4; ++kc)
                    s += agload(&a.gsp[((size_t)((g * 4 + kc) * 32 + bb)) * 256 + j]);
                gs[g] = s;
            }
            gs[0] += a.b_i[j]; gs[1] += a.b_f[j]; gs[2] += a.b_o[j];
            gs[3] += a.b_g1[j]; gs[4] += a.b_g2[j];
            float iv = sigm(gs[0]), fv = sigm(gs[1]), ov = sigm(gs[2]);
            float g1 = tanhf(gs[3]), g2 = tanhf(gs[4]);
            float nc = fv * agload(&csOld[bb * 256 + j]) + iv * g1;
            float nC = fv * agload(&CsOld[bb * 256 + j]) + iv * g2;
            if (ct == 0) {
                agstore(&csNew[bb * 256 + j], nc);
                agstore(&CsNew[bb * 256 + j], nC);
            }
            if (ct == 1 && tid == 0) agstore(&a.zsum[bb], 0.f);
            F[j] = nc;
            F[256 + j] = nC;
            F[512 + j] = ov;
            __syncthreads();
            int colL = tid & 31, kth = tid >> 5;
            int col = ct * 32 + colL;
            float part = 0.f;
            const float* wm = a.W_mlp + col;
            for (int i = 0; i < 64; ++i) {
                int k = kth * 64 + i;
                part += F[k] * wm[(size_t)k * 256];
            }
            F[768 + colL * 9 + kth] = part;
            __syncthreads();
            if (tid < 32) {
                int c2 = ct * 32 + tid;
                float m = a.b_mlp[c2];
#pragma unroll
                for (int kk = 0; kk < 8; ++kk) m += F[768 + tid * 9 + kk];
                float hv = F[512 + c2] * tanhf(m);
                agstore(&a.hst[bb * 256 + c2], hv);
                F[1056 + tid] = hv;
                agstore(&a.awf[bb * 256 + c2], 0.f);
            }
            __syncthreads();
            float acc = 0.f;
            const float* wd = a.W_dec + (size_t)(ct * 32) * 256 + tid;
#pragma unroll
            for (int kk = 0; kk < 32; ++kk) acc += F[1056 + kk] * wd[(size_t)kk * 256];
            agstore(&a.at2p[((size_t)(bb * 8 + ct)) * 256 + tid], acc);
        }
        gbar(a.slots, a.root, ++gen);
    }

    // epilogue: pred for t = 18
    if (bid >= 80 && bid < 237) pred_task2(a, S16, bid - 80, TMz - 1);
}

extern "C" void kernel_launch(void* const* d_in, const int* in_sizes, int n_in,
                              void* d_out, int out_size, void* d_ws, size_t ws_size,
                              hipStream_t stream) {
    const float* info  = (const float*)d_in[0];
    const float* rel   = (const float*)d_in[1];
    const int*   caps  = (const int*)d_in[2];
    const int*   lens  = (const int*)d_in[3];
    const float* emb   = (const float*)d_in[4];
    const float* W_enc = (const float*)d_in[5];
    const float* b_enc = (const float*)d_in[6];
    const float* W_dec = (const float*)d_in[7];
    const float* b_dec = (const float*)d_in[8];
    const float* W_full= (const float*)d_in[9];
    const float* b_full= (const float*)d_in[10];
    const float* W_i   = (const float*)d_in[11];
    const float* b_i   = (const float*)d_in[12];
    const float* W_f   = (const float*)d_in[13];
    const float* b_f   = (const float*)d_in[14];
    const float* W_o   = (const float*)d_in[15];
    const float* b_o   = (const float*)d_in[16];
    const float* W_g1  = (const float*)d_in[17];
    const float* b_g1  = (const float*)d_in[18];
    const float* W_g2  = (const float*)d_in[19];
    const float* b_g2  = (const float*)d_in[20];
    const float* W_mlp = (const float*)d_in[21];
    const float* b_mlp = (const float*)d_in[22];
    const float* W_fc  = (const float*)d_in[25];
    const float* b_fc  = (const float*)d_in[26];
    const float* W_ih  = (const float*)d_in[27];
    const float* b_ih  = (const float*)d_in[28];
    const float* W_ic  = (const float*)d_in[29];
    const float* b_ic  = (const float*)d_in[30];
    const float* W_iC  = (const float*)d_in[31];
    const float* b_iC  = (const float*)d_in[32];

    float* out = (float*)d_out;
    float* out_pred  = out;
    float* out_alpha = out + (size_t)Bz * TMz * Vz;
    float* out_order = out_alpha + (size_t)Bz * TMz * 1024;

    float* w = (float*)d_ws;
    float* ph   = w + WS_PH;
    float* pcp  = w + WS_PC;
    unsigned short* att1h = (unsigned short*)(w + WS_ATT1H);
    unsigned short* infoh = (unsigned short*)(w + WS_INFOH);
    float* expe = w + WS_EXPE;
    float* zsum = w + WS_ZSUM;
    float* awf  = w + WS_AWF;
    float* gsp  = w + WS_GSP;
    float* hst  = w + WS_HST;
    float* cst0 = w + WS_CST0;
    float* Cst0 = w + WS_CSTB0;
    float* cst1 = w + WS_CST1;
    float* Cst1 = w + WS_CSTB1;
    float* at2p = w + WS_AT2P;
    int*   ordp = (int*)(w + WS_INTS);
    int*   slp  = ordp + 32;
    int*   barmem = ordp + 64;
    float* pC   = w + WS_PCHC;
    unsigned short* wg16   = (unsigned short*)(w + WS_WG16);   // reuses pC region (dead after k_reduce3)
    unsigned short* wfcT16 = (unsigned short*)(w + WS_WFC16);  // optional extension

    int useWfc = (ws_size >= (size_t)WS_END_WFC * 4);

    k_sort<<<1, 64, 0, stream>>>(lens, out_order, ordp, slp, barmem);
    k_gemv2<<<512, 256, 0, stream>>>(info, ordp, W_ih, W_ic, ph, pcp);
    k_gemvC<<<128, 256, 0, stream>>>(rel, ordp, W_iC, pC);
    k_reduce3<<<96, 256, 0, stream>>>(ph, pcp, pC, b_ih, b_ic, b_iC, hst, cst0, Cst0);
    k_init2<<<4, 256, 0, stream>>>(hst, W_dec, at2p, awf, zsum);
    k_wg16<<<80, 256, 0, stream>>>(W_i, W_f, W_o, W_g1, W_g2, wg16);   // after k_reduce3 (pC dead)
    if (useWfc) k_wfc16<<<625, 256, 0, stream>>>(W_fc, wfcT16);
    k_att1<<<1024, 256, 0, stream>>>(info, ordp, W_enc, b_enc, att1h, infoh);

    KArgs ka;
    ka.info = info; ka.emb = emb; ka.W_dec = W_dec; ka.b_dec = b_dec;
    ka.W_full = W_full; ka.b_full = b_full;
    ka.b_i = b_i; ka.b_f = b_f; ka.b_o = b_o; ka.b_g1 = b_g1; ka.b_g2 = b_g2;
    ka.W_mlp = W_mlp; ka.b_mlp = b_mlp; ka.W_fc = W_fc; ka.b_fc = b_fc;
    ka.caps = caps;
    ka.att1h = att1h; ka.infoh = infoh;
    ka.wfcT16 = useWfc ? wfcT16 : (const unsigned short*)0;
    ka.wg16 = wg16;
    ka.expe = expe; ka.zsum = zsum; ka.awf = awf;
    ka.gsp = gsp; ka.hst = hst;
    ka.cst0 = cst0; ka.Cst0 = Cst0; ka.cst1 = cst1; ka.Cst1 = Cst1;
    ka.at2p = at2p;
    ka.ord = ordp; ka.slp = slp;
    ka.root = barmem; ka.slots = barmem + 64;
    ka.out_pred = out_pred; ka.out_alpha = out_alpha;

    k_steps<<<NBLK, 256, 0, stream>>>(ka);
}